// Round 10
// baseline (212.554 us; speedup 1.0000x reference)
//
#include <hip/hip_runtime.h>
#include <hip/hip_bf16.h>
#include <cstddef>
#include <cstdint>

// GINConvFFT round 10: round-7 structure + 4-blocks/CU zgemm with exact-once
// coalesced x reads, single-buffer pipelined K-loops (read frags -> refill),
// bn_final folded into bn_out.
//   prep2: MallC even col-slices=(1+eps)I+A_s; MT; Wt            (1280 blk)
//   zmsq : blocks 0-1023: Z[(b*64+o)][k*512+m] = Wt[k*64+o][:].x[b*512+m][:]
//          (tile 256i x 16m; x fp32 coalesced->VGPR->bf16->LDS; Wt via gl2lds)
//          blocks 1024-1055: MallC odd slices = M_s^2
//   ysum : Yh[ks][r][o] = half-K partial of MallC . Z^T          (512 blk)
//   bn_part: per-64-row partial sum/sumsq of Yh0+Yh1             (256 blk)
//   bn_out : stats (from partials) + normalize+relu+w2+b2        (256 blk)
#define B_   32
#define N_   512
#define D_   768
#define OUT_ 64
#define R_   (B_ * N_)

typedef unsigned short u16;
typedef __bf16 bf16x8 __attribute__((ext_vector_type(8)));
typedef float  f32x4  __attribute__((ext_vector_type(4)));
typedef unsigned short u16x8 __attribute__((ext_vector_type(8)));
typedef unsigned short u16x4 __attribute__((ext_vector_type(4)));

#define WAITVM(n) __asm__ __volatile__("s_waitcnt vmcnt(" #n ")" ::: "memory")
#define WAITLGKM() __asm__ __volatile__("s_waitcnt lgkmcnt(0)" ::: "memory")
#define SBAR()    __builtin_amdgcn_s_barrier()

__device__ __forceinline__ u16 f2bf(float f) {
    __hip_bfloat16 h = __float2bfloat16(f);
    return __builtin_bit_cast(u16, h);
}

__device__ __forceinline__ f32x4 mfma16(u16x8 a, u16x8 b, f32x4 c) {
    return __builtin_amdgcn_mfma_f32_16x16x32_bf16(
        __builtin_bit_cast(bf16x8, a), __builtin_bit_cast(bf16x8, b), c, 0, 0, 0);
}

__device__ __forceinline__ void gl2lds16(const void* g, void* l) {
    __builtin_amdgcn_global_load_lds(
        (const __attribute__((address_space(1))) unsigned int*)g,
        (__attribute__((address_space(3))) unsigned int*)l, 16, 0, 0);
}

// ---------------------------------------------------------------------------
// prep2: [0,512) build M (even MallC col slices) + MT | [512,1280) build Wt
// ---------------------------------------------------------------------------
__global__ __launch_bounds__(256) void prep2(
    const float* __restrict__ support, const float* __restrict__ weight,
    const float* __restrict__ epsp,
    u16* __restrict__ MallC, u16* __restrict__ MT, u16* __restrict__ Wt)
{
    const int blk = blockIdx.x, tid = threadIdx.x;
    __shared__ float t[32][33];
    if (blk < 512) {
        int s = blk >> 8, rem = blk & 255;
        int n0 = (rem >> 4) * 32, m0 = (rem & 15) * 32;
        const float f = 1.0f + epsp[0];
        const float* S = support + (size_t)s * 262144;
#pragma unroll
        for (int p = 0; p < 4; ++p) {
            int nl = p * 8 + (tid >> 5), ml = tid & 31;
            float v = S[(size_t)(n0 + nl) * 512 + m0 + ml];
            if (n0 + nl == m0 + ml) v += f;
            MallC[(size_t)(n0 + nl) * 2048 + s * 1024 + m0 + ml] = f2bf(v);
            t[nl][ml] = v;
        }
        __syncthreads();
#pragma unroll
        for (int p = 0; p < 4; ++p) {
            int ml = p * 8 + (tid >> 5), nl = tid & 31;
            MT[(size_t)s * 262144 + (size_t)(m0 + ml) * 512 + n0 + nl] = f2bf(t[nl][ml]);
        }
    } else {
        int idx = (blk - 512) * 256 + tid;          // 4*64*768 = 196608
        int k = idx / 49152, rem = idx % 49152;
        int o = rem / 768, d = rem % 768;
        int l = d >> 6, hh = d & 63;
        Wt[idx] = f2bf(weight[((size_t)l * 256 + hh * 4 + k) * 64 + o]);
    }
}

// ---------------------------------------------------------------------------
// zmsq:
//  blocks 0-1023: zgemm, tile 256i x 16m, K=768, BK=64, 12 iters.
//    mt=bid: b=mt>>5, mm0=(mt&31)*16. Wave wid owns i-rows wid*64..+63 (k=wid).
//    LDS: A 2 panels x 16 subs x 512 u16 (32 KB) | B 2 panels x 512 u16 (2 KB).
//    Pipeline: ds_read frags; lgkm0; bar; issue next loads; MFMA; vm waits; bar.
//  blocks 1024-1055: msq 128x128, K=512, BK=64 (single-buffer syncthreads).
// ---------------------------------------------------------------------------
__global__ __launch_bounds__(256) void zmsq(
    const u16* __restrict__ Wt, const float* __restrict__ x,
    const u16* __restrict__ MallC_in, const u16* __restrict__ MT,
    u16* __restrict__ Z, u16* __restrict__ MallC_out)
{
    __shared__ __align__(16) u16 SM[17408];          // 34 KB
    const int tid = threadIdx.x, lane = tid & 63, wid = tid >> 6;
    const int lrow = lane & 15, lk8 = (lane >> 4) * 8;
    const int q = lane >> 4;
    const int bid = blockIdx.x;

    if (bid < 1024) {
        const int mt = bid;
        const int b = mt >> 5, mm0 = (mt & 31) * 16;

        // A staging (gl2lds): 32 assignments, 8 per wave
        const u16* gsrcA[8]; u16* ldstA[8];
#pragma unroll
        for (int t = 0; t < 8; ++t) {
            int idx = wid * 8 + t;                  // [0,32)
            int pan = idx >> 4, sub = idx & 15;
            gsrcA[t] = Wt + (size_t)(sub * 16 + lrow) * 768 + pan * 32 + lk8;
            ldstA[t] = SM + pan * 8192 + sub * 512;
        }
        // B: thread t -> row r=t>>4, chunk kc=t&15 (4 floats)
        const int r = tid >> 4, kc = tid & 15;
        const float* gx = x + (size_t)(mt * 16 + r) * 768 + kc * 4;
        const int kin = kc * 4;
        const int pan = kin >> 5, kp = kin & 31;
        u16* bdst = SM + 16384 + pan * 512 + (kp >> 3) * 128 + r * 8 + (kp & 7);

        // prologue: iter 0
        f32x4 bv = *(const f32x4*)(gx);             // vm+1
#pragma unroll
        for (int t = 0; t < 8; ++t) gl2lds16(gsrcA[t], ldstA[t]);   // vm+8
        WAITVM(8);
        { u16x4 w; for (int j = 0; j < 4; ++j) w[j] = f2bf(bv[j]); *(u16x4*)bdst = w; }
        WAITVM(0); WAITLGKM();
        SBAR();

        f32x4 acc[4] = {};
        u16x8 Af[4][2], Bf[2];
#pragma unroll
        for (int kk = 0; kk < 12; ++kk) {
            // read frags for kk
#pragma unroll
            for (int fi = 0; fi < 4; ++fi)
#pragma unroll
                for (int p2 = 0; p2 < 2; ++p2)
                    Af[fi][p2] = *(const u16x8*)(SM + p2 * 8192 + (wid * 4 + fi) * 512 + lane * 8);
#pragma unroll
            for (int p2 = 0; p2 < 2; ++p2)
                Bf[p2] = *(const u16x8*)(SM + 16384 + p2 * 512 + lane * 8);
            WAITLGKM();
            SBAR();                                  // stage free
            if (kk < 11) {
                bv = *(const f32x4*)(gx + (kk + 1) * 64);            // vm+1
#pragma unroll
                for (int t = 0; t < 8; ++t) {
                    gl2lds16(gsrcA[t] + (kk + 1) * 64, ldstA[t]);    // vm+8
                }
            }
#pragma unroll
            for (int p2 = 0; p2 < 2; ++p2)
#pragma unroll
                for (int fi = 0; fi < 4; ++fi)
                    acc[fi] = mfma16(Af[fi][p2], Bf[p2], acc[fi]);
            if (kk < 11) {
                WAITVM(8);                           // B arrived
                { u16x4 w; for (int j = 0; j < 4; ++j) w[j] = f2bf(bv[j]); *(u16x4*)bdst = w; }
                WAITVM(0); WAITLGKM();
                SBAR();
            }
        }
        // epilogue: direct stores (k = wid)
#pragma unroll
        for (int fi = 0; fi < 4; ++fi)
#pragma unroll
            for (int rr = 0; rr < 4; ++rr) {
                int o = fi * 16 + q * 4 + rr;
                Z[(size_t)(b * 64 + o) * 2048 + wid * 512 + mm0 + lrow] = f2bf(acc[fi][rr]);
            }
    } else {
        // msq: 128x128, K=512, BK=64, single-buffered (32 blocks)
        const int wr = wid >> 1, wc = wid & 1;
        int lb = bid - 1024;
        int s = lb >> 4, rem = lb & 15;
        int i0 = (rem >> 2) * 128, j0 = (rem & 3) * 128;
        const u16* Ab = MallC_in + s * 1024;         // stride 2048
        const u16* Bb = MT + (size_t)s * 262144;     // stride 512

        const u16* gsrc[8]; u16* ldst[8];
#pragma unroll
        for (int t = 0; t < 8; ++t) {
            int idx = wid * 8 + t;
            int pan = idx >> 4, q2 = idx & 15;
            if (q2 < 8) {
                gsrc[t] = Ab + (size_t)(i0 + q2 * 16 + lrow) * 2048 + pan * 32 + lk8;
                ldst[t] = SM + pan * 8192 + q2 * 512;
            } else {
                gsrc[t] = Bb + (size_t)(j0 + (q2 - 8) * 16 + lrow) * 512 + pan * 32 + lk8;
                ldst[t] = SM + pan * 8192 + 4096 + (q2 - 8) * 512;
            }
        }
        f32x4 acc[4][4] = {};
        for (int kk = 0; kk < 8; ++kk) {
#pragma unroll
            for (int t = 0; t < 8; ++t) gl2lds16(gsrc[t], ldst[t]);
#pragma unroll
            for (int t = 0; t < 8; ++t) gsrc[t] += 64;
            __syncthreads();
#pragma unroll
            for (int pan = 0; pan < 2; ++pan) {
                u16x8 af[4], bq[4];
#pragma unroll
                for (int f = 0; f < 4; ++f)
                    af[f] = *(const u16x8*)(SM + pan * 8192 + (wr * 4 + f) * 512 + lane * 8);
#pragma unroll
                for (int f = 0; f < 4; ++f)
                    bq[f] = *(const u16x8*)(SM + pan * 8192 + 4096 + (wc * 4 + f) * 512 + lane * 8);
#pragma unroll
                for (int fi = 0; fi < 4; ++fi)
#pragma unroll
                    for (int fj = 0; fj < 4; ++fj)
                        acc[fi][fj] = mfma16(af[fi], bq[fj], acc[fi][fj]);
            }
            __syncthreads();
        }
#pragma unroll
        for (int fi = 0; fi < 4; ++fi)
#pragma unroll
            for (int fj = 0; fj < 4; ++fj)
#pragma unroll
                for (int rr = 0; rr < 4; ++rr) {
                    int n = i0 + wr * 64 + fi * 16 + q * 4 + rr;
                    int c = j0 + wc * 64 + fj * 16 + lrow;
                    MallC_out[(size_t)n * 2048 + (2 * s + 1) * 512 + c] = f2bf(acc[fi][fj][rr]);
                }
    }
}

// ---------------------------------------------------------------------------
// ysum: 512 blocks: rt = bid&255, ks = bid>>8. Tile 64r x 64o, K=1024 half,
// BK=64, 16 iters, single-buffer pipelined. Waves 2x2 of 32x32.
// ---------------------------------------------------------------------------
__global__ __launch_bounds__(256) void ysum(
    const u16* __restrict__ G, const u16* __restrict__ Z, float* __restrict__ Yh)
{
    __shared__ __align__(16) u16 SM[8192];           // A 2x(4x512) | B 2x(4x512)
    const int tid = threadIdx.x, lane = tid & 63, wid = tid >> 6;
    const int wr = wid >> 1, wc = wid & 1;
    const int lrow = lane & 15, lk8 = (lane >> 4) * 8;
    const int bid = blockIdx.x;
    const int rt = bid & 255, ks = bid >> 8;
    const int r0 = rt * 64, b = rt >> 3, n0 = r0 & 511;
    const size_t km0 = (size_t)ks * 1024;

    const u16* gsrc[4]; u16* ldst[4];
#pragma unroll
    for (int t = 0; t < 4; ++t) {
        int idx = wid * 4 + t;                       // [0,16)
        if (idx < 8) {
            int pan = idx >> 2, sub = idx & 3;
            gsrc[t] = G + (size_t)(n0 + sub * 16 + lrow) * 2048 + km0 + pan * 32 + lk8;
            ldst[t] = SM + pan * 2048 + sub * 512;
        } else {
            int i2 = idx - 8;
            int pan = i2 >> 2, sub = i2 & 3;
            gsrc[t] = Z + (size_t)(b * 64 + sub * 16 + lrow) * 2048 + km0 + pan * 32 + lk8;
            ldst[t] = SM + 4096 + pan * 2048 + sub * 512;
        }
    }
    // prologue
#pragma unroll
    for (int t = 0; t < 4; ++t) gl2lds16(gsrc[t], ldst[t]);
    WAITVM(0);
    SBAR();

    f32x4 acc[2][2] = {};
    u16x8 Af[2][2], Bfr[2][2];
#pragma unroll
    for (int kk = 0; kk < 16; ++kk) {
#pragma unroll
        for (int p2 = 0; p2 < 2; ++p2) {
#pragma unroll
            for (int f = 0; f < 2; ++f) {
                Af[f][p2]  = *(const u16x8*)(SM + p2 * 2048 + (wr * 2 + f) * 512 + lane * 8);
                Bfr[f][p2] = *(const u16x8*)(SM + 4096 + p2 * 2048 + (wc * 2 + f) * 512 + lane * 8);
            }
        }
        WAITLGKM();
        SBAR();
        if (kk < 15) {
#pragma unroll
            for (int t = 0; t < 4; ++t) gl2lds16(gsrc[t] + (kk + 1) * 64, ldst[t]);
        }
#pragma unroll
        for (int p2 = 0; p2 < 2; ++p2)
#pragma unroll
            for (int fi = 0; fi < 2; ++fi)
#pragma unroll
                for (int fj = 0; fj < 2; ++fj)
                    acc[fi][fj] = mfma16(Af[fi][p2], Bfr[fj][p2], acc[fi][fj]);
        if (kk < 15) {
            WAITVM(0);
            SBAR();
        }
    }
    const int q = lane >> 4;
    float* Yk = Yh + (size_t)ks * R_ * 64;
#pragma unroll
    for (int fi = 0; fi < 2; ++fi)
#pragma unroll
        for (int fj = 0; fj < 2; ++fj)
#pragma unroll
            for (int rr = 0; rr < 4; ++rr) {
                int r2 = r0 + wr * 32 + fi * 16 + q * 4 + rr;
                int o  = wc * 32 + fj * 16 + lrow;
                Yk[(size_t)r2 * 64 + o] = acc[fi][fj][rr];
            }
}

// ---------------------------------------------------------------------------
// bn_part: grid 256, block j: rows j*64..+63, v = Yh0+Yh1, partial sum/sumsq.
// ---------------------------------------------------------------------------
__global__ __launch_bounds__(256) void bn_part(
    const float* __restrict__ Yh, float* __restrict__ part)
{
    const int blk = blockIdx.x, tid = threadIdx.x;
    const int o = tid & 63, g = tid >> 6;
    float s = 0.f, s2 = 0.f;
#pragma unroll
    for (int p = 0; p < 16; ++p) {
        int r = blk * 64 + p * 4 + g;
        size_t off = (size_t)r * 64 + o;
        float v = Yh[off] + Yh[(size_t)R_ * 64 + off];
        s += v; s2 += v * v;
    }
    __shared__ float ls[4][64], ls2[4][64];
    ls[g][o] = s; ls2[g][o] = s2;
    __syncthreads();
    if (tid < 64) {
        float t = 0.f, t2 = 0.f;
#pragma unroll
        for (int g2 = 0; g2 < 4; ++g2) { t += ls[g2][tid]; t2 += ls2[g2][tid]; }
        part[blk * 128 + tid]      = t;
        part[blk * 128 + 64 + tid] = t2;
    }
}

// ---------------------------------------------------------------------------
// bn_out: inline stats from partials (every block), then normalize+relu+w2+b2.
// ---------------------------------------------------------------------------
__global__ __launch_bounds__(256) void bn_out(
    const float* __restrict__ Yh, const float* __restrict__ part,
    const float* __restrict__ gamma, const float* __restrict__ beta,
    const float* __restrict__ w2, const float* __restrict__ b2,
    float* __restrict__ out)
{
    __shared__ float ys[64 * 68];
    __shared__ float w2s[64 * 65];
    __shared__ float red[4][64], red2[4][64];
    __shared__ float sa[64], sh[64];
    const int tid = threadIdx.x;
    const int r0 = blockIdx.x * 64;
    const int o = tid & 63, g = tid >> 6;
    // stats
    {
        float s = 0.f, s2 = 0.f;
        for (int p = g; p < 256; p += 4) {
            s  += part[p * 128 + o];
            s2 += part[p * 128 + 64 + o];
        }
        red[g][o] = s; red2[g][o] = s2;
    }
#pragma unroll
    for (int i = 0; i < 16; ++i) {
        int idx = tid + i * 256;
        w2s[(idx >> 6) * 65 + (idx & 63)] = w2[idx];
    }
    __syncthreads();
    if (tid < 64) {
        float t0 = red[0][tid] + red[1][tid] + red[2][tid] + red[3][tid];
        float t2 = red2[0][tid] + red2[1][tid] + red2[2][tid] + red2[3][tid];
        float mean = t0 * (1.0f / R_);
        float var  = t2 * (1.0f / R_) - mean * mean;
        float a = rsqrtf(var + 1e-5f) * gamma[tid];
        sa[tid] = a;
        sh[tid] = beta[tid] - mean * a;
    }
    __syncthreads();
    {
        float a = sa[o], bsh = sh[o];
#pragma unroll
        for (int p = 0; p < 16; ++p) {
            int rl = p * 4 + g;
            size_t off = (size_t)(r0 + rl) * 64 + o;
            float v = Yh[off] + Yh[(size_t)R_ * 64 + off];
            ys[o * 68 + rl] = fmaxf(fmaf(v, a, bsh), 0.f);
        }
    }
    __syncthreads();
    float acc[16];
    float bb = b2[o];
#pragma unroll
    for (int j = 0; j < 16; ++j) acc[j] = bb;
    for (int c = 0; c < 64; ++c) {
        float wv = w2s[o * 65 + c];
        const float* yr = ys + c * 68 + g * 16;
        f32x4 y0 = *(const f32x4*)(yr);
        f32x4 y1 = *(const f32x4*)(yr + 4);
        f32x4 y2 = *(const f32x4*)(yr + 8);
        f32x4 y3 = *(const f32x4*)(yr + 12);
#pragma unroll
        for (int j = 0; j < 4; ++j) {
            acc[j]      = fmaf(wv, y0[j], acc[j]);
            acc[4 + j]  = fmaf(wv, y1[j], acc[4 + j]);
            acc[8 + j]  = fmaf(wv, y2[j], acc[8 + j]);
            acc[12 + j] = fmaf(wv, y3[j], acc[12 + j]);
        }
    }
#pragma unroll
    for (int j = 0; j < 16; ++j)
        out[(size_t)(r0 + g * 16 + j) * OUT_ + o] = acc[j];
}

// ---------------------------------------------------------------------------
extern "C" void kernel_launch(void* const* d_in, const int* in_sizes, int n_in,
                              void* d_out, int out_size, void* d_ws, size_t ws_size,
                              hipStream_t stream)
{
    const float* x       = (const float*)d_in[0];
    const float* support = (const float*)d_in[1];
    const float* weight  = (const float*)d_in[2];
    const float* eps     = (const float*)d_in[3];
    const float* gamma   = (const float*)d_in[4];
    const float* beta    = (const float*)d_in[5];
    const float* w2      = (const float*)d_in[6];
    const float* b2      = (const float*)d_in[7];
    float* out = (float*)d_out;

    char* ws = (char*)d_ws;
    u16*   MallC = (u16*)(ws);                      //  2,097,152  [512][2048]
    u16*   MT    = (u16*)(ws + 2097152);            //  1,048,576
    u16*   Wt    = (u16*)(ws + 3145728);            //    393,216  [256][768]
    u16*   Z     = (u16*)(ws + 3538944);            //  8,388,608  [2048][2048]
    float* Yh    = (float*)(ws + 11927552);         //  8,388,608  (2 halves)
    float* part  = (float*)(ws + 20316160);         //    131,072

    prep2  <<<1280, 256, 0, stream>>>(support, weight, eps, MallC, MT, Wt);
    zmsq   <<<1056, 256, 0, stream>>>(Wt, x, MallC, MT, Z, MallC);
    ysum   <<<512,  256, 0, stream>>>(MallC, Z, Yh);
    bn_part<<<256,  256, 0, stream>>>(Yh, part);
    bn_out <<<256,  256, 0, stream>>>(Yh, part, gamma, beta, w2, b2, out);
}

// Round 11
// 182.210 us; speedup vs baseline: 1.1665x; 1.1665x over previous
//
#include <hip/hip_runtime.h>
#include <hip/hip_bf16.h>
#include <cstddef>
#include <cstdint>

// GINConvFFT round 11: occupancy-first. All GEMM kernels 64x64 tiles,
// 1024+ blocks (4 blocks/CU), simple syncthreads K-loops (the r3-proven
// structure), conflict-free ds_write_b128 fp32->bf16 B staging in zgemm.
//   prep2: MallC even col-slices=(1+eps)I+A_s; MT; Wt          (1280 blk)
//   zmsq : blocks 0-1023: Z[(b*64+o)][k*512+m] = Wt[k*64+o][:].x[b*512+m][:]
//          (64x64 tile per (k,b,mtile); x fp32 read directly, cvt in VGPR)
//          blocks 1024-1151: MallC odd slices = M_s^2 (64x64 tiles)
//   ysum : Yh[kq][r][o] = quarter-K partial of MallC . Z^T     (1024 blk)
//   bn_part: per-64-row partial sum/sumsq of sum of 4 quarters (256 blk)
//   bn_out : inline stats + normalize+relu+w2+b2               (256 blk)
#define B_   32
#define N_   512
#define D_   768
#define OUT_ 64
#define R_   (B_ * N_)

typedef unsigned short u16;
typedef __bf16 bf16x8 __attribute__((ext_vector_type(8)));
typedef float  f32x4  __attribute__((ext_vector_type(4)));
typedef unsigned short u16x8 __attribute__((ext_vector_type(8)));

__device__ __forceinline__ u16 f2bf(float f) {
    __hip_bfloat16 h = __float2bfloat16(f);
    return __builtin_bit_cast(u16, h);
}

__device__ __forceinline__ f32x4 mfma16(u16x8 a, u16x8 b, f32x4 c) {
    return __builtin_amdgcn_mfma_f32_16x16x32_bf16(
        __builtin_bit_cast(bf16x8, a), __builtin_bit_cast(bf16x8, b), c, 0, 0, 0);
}

__device__ __forceinline__ void gl2lds16(const void* g, void* l) {
    __builtin_amdgcn_global_load_lds(
        (const __attribute__((address_space(1))) unsigned int*)g,
        (__attribute__((address_space(3))) unsigned int*)l, 16, 0, 0);
}

// ---------------------------------------------------------------------------
// prep2: [0,512) build M (even MallC col slices) + MT | [512,1280) build Wt
// ---------------------------------------------------------------------------
__global__ __launch_bounds__(256) void prep2(
    const float* __restrict__ support, const float* __restrict__ weight,
    const float* __restrict__ epsp,
    u16* __restrict__ MallC, u16* __restrict__ MT, u16* __restrict__ Wt)
{
    const int blk = blockIdx.x, tid = threadIdx.x;
    __shared__ float t[32][33];
    if (blk < 512) {
        int s = blk >> 8, rem = blk & 255;
        int n0 = (rem >> 4) * 32, m0 = (rem & 15) * 32;
        const float f = 1.0f + epsp[0];
        const float* S = support + (size_t)s * 262144;
#pragma unroll
        for (int p = 0; p < 4; ++p) {
            int nl = p * 8 + (tid >> 5), ml = tid & 31;
            float v = S[(size_t)(n0 + nl) * 512 + m0 + ml];
            if (n0 + nl == m0 + ml) v += f;
            MallC[(size_t)(n0 + nl) * 2048 + s * 1024 + m0 + ml] = f2bf(v);
            t[nl][ml] = v;
        }
        __syncthreads();
#pragma unroll
        for (int p = 0; p < 4; ++p) {
            int ml = p * 8 + (tid >> 5), nl = tid & 31;
            MT[(size_t)s * 262144 + (size_t)(m0 + ml) * 512 + n0 + nl] = f2bf(t[nl][ml]);
        }
    } else {
        int idx = (blk - 512) * 256 + tid;          // 4*64*768 = 196608
        int k = idx / 49152, rem = idx % 49152;
        int o = rem / 768, d = rem % 768;
        int l = d >> 6, hh = d & 63;
        Wt[idx] = f2bf(weight[((size_t)l * 256 + hh * 4 + k) * 64 + o]);
    }
}

// ---------------------------------------------------------------------------
// zmsq: 64x64 tiles everywhere, 4 blocks/CU.
//  blocks 0-1023: zgemm. k = bid>>8; r2 = bid&255: b = r2>>3, m0 = (r2&7)*64.
//    A = Wt rows k*64..+63 (gl2lds). B = x rows b*512+m0..+63 (fp32 VGPR->cvt
//    ->ds_write_b128). K=768, BK=64, 12 iters. Waves 2x2 of 32x32.
//  blocks 1024-1151: msq. lb=bid-1024: s=lb>>6, i0=((lb>>3)&7)*64, j0=(lb&7)*64.
//    A = MallC even slice rows, B = MT rows (both gl2lds). K=512, 8 iters.
// LDS: A 4096 u16 (p*2048+sub*512) | B at +4096 same layout. 16 KB.
// ---------------------------------------------------------------------------
__global__ __launch_bounds__(256, 4) void zmsq(
    const u16* __restrict__ Wt, const float* __restrict__ x,
    const u16* __restrict__ MallC_in, const u16* __restrict__ MT,
    u16* __restrict__ Z, u16* __restrict__ MallC_out)
{
    __shared__ __align__(16) u16 SM[8192];           // 16 KB
    const int tid = threadIdx.x, lane = tid & 63, wid = tid >> 6;
    const int wr = wid >> 1, wc = wid & 1;
    const int lrow = lane & 15, lk8 = (lane >> 4) * 8;
    const int q = lane >> 4;
    const int bid = blockIdx.x;

    f32x4 acc[2][2] = {};

    if (bid < 1024) {
        const int k = bid >> 8, r2 = bid & 255;
        const int b = r2 >> 3, m0 = (r2 & 7) * 64;

        // A staging: 8 gl2lds insts, 2 per wave
        const u16* gsrcA[2]; u16* ldstA[2];
#pragma unroll
        for (int t = 0; t < 2; ++t) {
            int idx = wid * 2 + t;                   // [0,8)
            int p = idx >> 2, sub = idx & 3;
            gsrcA[t] = Wt + (size_t)(k * 64 + sub * 16 + lrow) * 768 + p * 32 + lk8;
            ldstA[t] = SM + p * 2048 + sub * 512;
        }
        // B: thread t -> row r=t&63, kq=t>>6 (16 k-elems each)
        const int r = tid & 63, kq = tid >> 6;
        const float* gx = x + (size_t)(b * 512 + m0 + r) * 768 + kq * 16;
        u16* bdst = SM + 4096 + (kq >> 1) * 2048 + (r >> 4) * 512
                  + (kq & 1) * 256 + (r & 15) * 8;

        for (int kk = 0; kk < 12; ++kk) {
#pragma unroll
            for (int t = 0; t < 2; ++t) gl2lds16(gsrcA[t], ldstA[t]);
#pragma unroll
            for (int t = 0; t < 2; ++t) gsrcA[t] += 64;
            f32x4 a0 = *(const f32x4*)(gx);
            f32x4 a1 = *(const f32x4*)(gx + 4);
            f32x4 a2 = *(const f32x4*)(gx + 8);
            f32x4 a3 = *(const f32x4*)(gx + 12);
            gx += 64;
            u16x8 w0, w1;
#pragma unroll
            for (int j = 0; j < 4; ++j) {
                w0[j] = f2bf(a0[j]); w0[4 + j] = f2bf(a1[j]);
                w1[j] = f2bf(a2[j]); w1[4 + j] = f2bf(a3[j]);
            }
            *(u16x8*)(bdst)       = w0;
            *(u16x8*)(bdst + 128) = w1;
            __syncthreads();
#pragma unroll
            for (int p = 0; p < 2; ++p) {
                u16x8 af[2], bq[2];
#pragma unroll
                for (int f = 0; f < 2; ++f)
                    af[f] = *(const u16x8*)(SM + p * 2048 + (wr * 2 + f) * 512 + lane * 8);
#pragma unroll
                for (int f = 0; f < 2; ++f)
                    bq[f] = *(const u16x8*)(SM + 4096 + p * 2048 + (wc * 2 + f) * 512 + lane * 8);
#pragma unroll
                for (int fi = 0; fi < 2; ++fi)
#pragma unroll
                    for (int fj = 0; fj < 2; ++fj)
                        acc[fi][fj] = mfma16(af[fi], bq[fj], acc[fi][fj]);
            }
            __syncthreads();
        }
        // epilogue: per-wave repack 32x32 (stride 40 u16), vector stores
        u16* Rw = SM + wid * 1280;
#pragma unroll
        for (int fi = 0; fi < 2; ++fi)
#pragma unroll
            for (int fj = 0; fj < 2; ++fj)
#pragma unroll
                for (int rr = 0; rr < 4; ++rr)
                    Rw[(fi * 16 + q * 4 + rr) * 40 + fj * 16 + lrow] = f2bf(acc[fi][fj][rr]);
        __syncthreads();
        const int r3 = lane >> 1, cc = (lane & 1) * 16;
        u16x8 v0 = *(const u16x8*)(Rw + r3 * 40 + cc);
        u16x8 v1 = *(const u16x8*)(Rw + r3 * 40 + cc + 8);
        u16* zp = Z + (size_t)(b * 64 + wr * 32 + r3) * 2048 + k * 512 + m0 + wc * 32 + cc;
        *(u16x8*)(zp)     = v0;
        *(u16x8*)(zp + 8) = v1;
    } else {
        const int lb = bid - 1024;
        const int s = lb >> 6, i0 = ((lb >> 3) & 7) * 64, j0 = (lb & 7) * 64;

        const u16* gsrc[4]; u16* ldst[4];
#pragma unroll
        for (int t = 0; t < 4; ++t) {
            int idx = wid * 4 + t;                   // [0,16)
            if (idx < 8) {
                int p = idx >> 2, sub = idx & 3;
                gsrc[t] = MallC_in + (size_t)(i0 + sub * 16 + lrow) * 2048 + s * 1024 + p * 32 + lk8;
                ldst[t] = SM + p * 2048 + sub * 512;
            } else {
                int i2 = idx - 8;
                int p = i2 >> 2, sub = i2 & 3;
                gsrc[t] = MT + (size_t)s * 262144 + (size_t)(j0 + sub * 16 + lrow) * 512 + p * 32 + lk8;
                ldst[t] = SM + 4096 + p * 2048 + sub * 512;
            }
        }
        for (int kk = 0; kk < 8; ++kk) {
#pragma unroll
            for (int t = 0; t < 4; ++t) gl2lds16(gsrc[t], ldst[t]);
#pragma unroll
            for (int t = 0; t < 4; ++t) gsrc[t] += 64;
            __syncthreads();
#pragma unroll
            for (int p = 0; p < 2; ++p) {
                u16x8 af[2], bq[2];
#pragma unroll
                for (int f = 0; f < 2; ++f)
                    af[f] = *(const u16x8*)(SM + p * 2048 + (wr * 2 + f) * 512 + lane * 8);
#pragma unroll
                for (int f = 0; f < 2; ++f)
                    bq[f] = *(const u16x8*)(SM + 4096 + p * 2048 + (wc * 2 + f) * 512 + lane * 8);
#pragma unroll
                for (int fi = 0; fi < 2; ++fi)
#pragma unroll
                    for (int fj = 0; fj < 2; ++fj)
                        acc[fi][fj] = mfma16(af[fi], bq[fj], acc[fi][fj]);
            }
            __syncthreads();
        }
#pragma unroll
        for (int fi = 0; fi < 2; ++fi)
#pragma unroll
            for (int fj = 0; fj < 2; ++fj)
#pragma unroll
                for (int rr = 0; rr < 4; ++rr) {
                    int n = i0 + wr * 32 + fi * 16 + q * 4 + rr;
                    int c = j0 + wc * 32 + fj * 16 + lrow;
                    MallC_out[(size_t)n * 2048 + (2 * s + 1) * 512 + c] = f2bf(acc[fi][fj][rr]);
                }
    }
}

// ---------------------------------------------------------------------------
// ysum: 1024 blocks (4/CU). kq = bid>>8, rt = bid&255: r0 = rt*64, b = rt>>3,
// n0 = r0&511. Tile 64r x 64o, K=512 (quarter), BK=64, 8 iters.
// Yh[kq][r][o] = sum_{m} MallC[n][kq*512+m] * Z[(b*64+o)][kq*512+m]
// ---------------------------------------------------------------------------
__global__ __launch_bounds__(256, 4) void ysum(
    const u16* __restrict__ G, const u16* __restrict__ Z, float* __restrict__ Yh)
{
    __shared__ __align__(16) u16 SM[8192];
    const int tid = threadIdx.x, lane = tid & 63, wid = tid >> 6;
    const int wr = wid >> 1, wc = wid & 1;
    const int lrow = lane & 15, lk8 = (lane >> 4) * 8;
    const int bid = blockIdx.x;
    const int kq = bid >> 8, rt = bid & 255;
    const int r0 = rt * 64, b = rt >> 3, n0 = r0 & 511;

    const u16* gsrc[4]; u16* ldst[4];
#pragma unroll
    for (int t = 0; t < 4; ++t) {
        int idx = wid * 4 + t;
        if (idx < 8) {
            int p = idx >> 2, sub = idx & 3;
            gsrc[t] = G + (size_t)(n0 + sub * 16 + lrow) * 2048 + kq * 512 + p * 32 + lk8;
            ldst[t] = SM + p * 2048 + sub * 512;
        } else {
            int i2 = idx - 8;
            int p = i2 >> 2, sub = i2 & 3;
            gsrc[t] = Z + (size_t)(b * 64 + sub * 16 + lrow) * 2048 + kq * 512 + p * 32 + lk8;
            ldst[t] = SM + 4096 + p * 2048 + sub * 512;
        }
    }
    f32x4 acc[2][2] = {};
    for (int kk = 0; kk < 8; ++kk) {
#pragma unroll
        for (int t = 0; t < 4; ++t) gl2lds16(gsrc[t], ldst[t]);
#pragma unroll
        for (int t = 0; t < 4; ++t) gsrc[t] += 64;
        __syncthreads();
#pragma unroll
        for (int p = 0; p < 2; ++p) {
            u16x8 af[2], bq[2];
#pragma unroll
            for (int f = 0; f < 2; ++f)
                af[f] = *(const u16x8*)(SM + p * 2048 + (wr * 2 + f) * 512 + lane * 8);
#pragma unroll
            for (int f = 0; f < 2; ++f)
                bq[f] = *(const u16x8*)(SM + 4096 + p * 2048 + (wc * 2 + f) * 512 + lane * 8);
#pragma unroll
            for (int fi = 0; fi < 2; ++fi)
#pragma unroll
                for (int fj = 0; fj < 2; ++fj)
                    acc[fi][fj] = mfma16(af[fi], bq[fj], acc[fi][fj]);
        }
        __syncthreads();
    }
    const int q = lane >> 4;
    float* Yk = Yh + (size_t)kq * R_ * 64;
#pragma unroll
    for (int fi = 0; fi < 2; ++fi)
#pragma unroll
        for (int fj = 0; fj < 2; ++fj)
#pragma unroll
            for (int rr = 0; rr < 4; ++rr) {
                int r2 = r0 + wr * 32 + fi * 16 + q * 4 + rr;
                int o  = wc * 32 + fj * 16 + lrow;
                Yk[(size_t)r2 * 64 + o] = acc[fi][fj][rr];
            }
}

// ---------------------------------------------------------------------------
// bn_part: grid 256, block j: rows j*64..+63, v = sum of 4 Yh quarters.
// ---------------------------------------------------------------------------
__global__ __launch_bounds__(256) void bn_part(
    const float* __restrict__ Yh, float* __restrict__ part)
{
    const int blk = blockIdx.x, tid = threadIdx.x;
    const int o = tid & 63, g = tid >> 6;
    float s = 0.f, s2 = 0.f;
#pragma unroll
    for (int p = 0; p < 16; ++p) {
        int r = blk * 64 + p * 4 + g;
        size_t off = (size_t)r * 64 + o;
        float v = Yh[off] + Yh[(size_t)R_ * 64 + off]
                + Yh[(size_t)2 * R_ * 64 + off] + Yh[(size_t)3 * R_ * 64 + off];
        s += v; s2 += v * v;
    }
    __shared__ float ls[4][64], ls2[4][64];
    ls[g][o] = s; ls2[g][o] = s2;
    __syncthreads();
    if (tid < 64) {
        float t = 0.f, t2 = 0.f;
#pragma unroll
        for (int g2 = 0; g2 < 4; ++g2) { t += ls[g2][tid]; t2 += ls2[g2][tid]; }
        part[blk * 128 + tid]      = t;
        part[blk * 128 + 64 + tid] = t2;
    }
}

// ---------------------------------------------------------------------------
// bn_out: inline stats from partials, then normalize+relu+w2+b2.
// ---------------------------------------------------------------------------
__global__ __launch_bounds__(256) void bn_out(
    const float* __restrict__ Yh, const float* __restrict__ part,
    const float* __restrict__ gamma, const float* __restrict__ beta,
    const float* __restrict__ w2, const float* __restrict__ b2,
    float* __restrict__ out)
{
    __shared__ float ys[64 * 68];
    __shared__ float w2s[64 * 65];
    __shared__ float red[4][64], red2[4][64];
    __shared__ float sa[64], sh[64];
    const int tid = threadIdx.x;
    const int r0 = blockIdx.x * 64;
    const int o = tid & 63, g = tid >> 6;
    {
        float s = 0.f, s2 = 0.f;
        for (int p = g; p < 256; p += 4) {
            s  += part[p * 128 + o];
            s2 += part[p * 128 + 64 + o];
        }
        red[g][o] = s; red2[g][o] = s2;
    }
#pragma unroll
    for (int i = 0; i < 16; ++i) {
        int idx = tid + i * 256;
        w2s[(idx >> 6) * 65 + (idx & 63)] = w2[idx];
    }
    __syncthreads();
    if (tid < 64) {
        float t0 = red[0][tid] + red[1][tid] + red[2][tid] + red[3][tid];
        float t2 = red2[0][tid] + red2[1][tid] + red2[2][tid] + red2[3][tid];
        float mean = t0 * (1.0f / R_);
        float var  = t2 * (1.0f / R_) - mean * mean;
        float a = rsqrtf(var + 1e-5f) * gamma[tid];
        sa[tid] = a;
        sh[tid] = beta[tid] - mean * a;
    }
    __syncthreads();
    {
        float a = sa[o], bsh = sh[o];
#pragma unroll
        for (int p = 0; p < 16; ++p) {
            int rl = p * 4 + g;
            size_t off = (size_t)(r0 + rl) * 64 + o;
            float v = Yh[off] + Yh[(size_t)R_ * 64 + off]
                    + Yh[(size_t)2 * R_ * 64 + off] + Yh[(size_t)3 * R_ * 64 + off];
            ys[o * 68 + rl] = fmaxf(fmaf(v, a, bsh), 0.f);
        }
    }
    __syncthreads();
    float acc[16];
    float bb = b2[o];
#pragma unroll
    for (int j = 0; j < 16; ++j) acc[j] = bb;
    for (int c = 0; c < 64; ++c) {
        float wv = w2s[o * 65 + c];
        const float* yr = ys + c * 68 + g * 16;
        f32x4 y0 = *(const f32x4*)(yr);
        f32x4 y1 = *(const f32x4*)(yr + 4);
        f32x4 y2 = *(const f32x4*)(yr + 8);
        f32x4 y3 = *(const f32x4*)(yr + 12);
#pragma unroll
        for (int j = 0; j < 4; ++j) {
            acc[j]      = fmaf(wv, y0[j], acc[j]);
            acc[4 + j]  = fmaf(wv, y1[j], acc[4 + j]);
            acc[8 + j]  = fmaf(wv, y2[j], acc[8 + j]);
            acc[12 + j] = fmaf(wv, y3[j], acc[12 + j]);
        }
    }
#pragma unroll
    for (int j = 0; j < 16; ++j)
        out[(size_t)(r0 + g * 16 + j) * OUT_ + o] = acc[j];
}

// ---------------------------------------------------------------------------
extern "C" void kernel_launch(void* const* d_in, const int* in_sizes, int n_in,
                              void* d_out, int out_size, void* d_ws, size_t ws_size,
                              hipStream_t stream)
{
    const float* x       = (const float*)d_in[0];
    const float* support = (const float*)d_in[1];
    const float* weight  = (const float*)d_in[2];
    const float* eps     = (const float*)d_in[3];
    const float* gamma   = (const float*)d_in[4];
    const float* beta    = (const float*)d_in[5];
    const float* w2      = (const float*)d_in[6];
    const float* b2      = (const float*)d_in[7];
    float* out = (float*)d_out;

    char* ws = (char*)d_ws;
    u16*   MallC = (u16*)(ws);                      //  2,097,152  [512][2048]
    u16*   MT    = (u16*)(ws + 2097152);            //  1,048,576
    u16*   Wt    = (u16*)(ws + 3145728);            //    393,216  [256][768]
    u16*   Z     = (u16*)(ws + 3538944);            //  8,388,608  [2048][2048]
    float* Yh    = (float*)(ws + 11927552);         // 16,777,216  (4 quarters)
    float* part  = (float*)(ws + 28704768);         //    131,072

    prep2  <<<1280, 256, 0, stream>>>(support, weight, eps, MallC, MT, Wt);
    zmsq   <<<1152, 256, 0, stream>>>(Wt, x, MallC, MT, Z, MallC);
    ysum   <<<1024, 256, 0, stream>>>(MallC, Z, Yh);
    bn_part<<<256,  256, 0, stream>>>(Yh, part);
    bn_out <<<256,  256, 0, stream>>>(Yh, part, gamma, beta, w2, b2, out);
}

// Round 12
// 171.208 us; speedup vs baseline: 1.2415x; 1.0643x over previous
//
#include <hip/hip_runtime.h>
#include <hip/hip_bf16.h>
#include <cstddef>
#include <cstdint>

// GINConvFFT round 12: r11 + coalesced B-path (sector-aligned x reads) and
// co-XCD k-duplicate swizzle in zgemm.
//   prep2: MallC even col-slices=(1+eps)I+A_s; MT; Wt          (1280 blk)
//   zmsq : blocks 0-1023: Z[(b*64+o)][k*512+m] = Wt[k*64+o][:].x[b*512+m][:]
//          (64x64 tile; x fp32 read 4-lanes-per-row contiguous, cvt in VGPR)
//          blocks 1024-1151: MallC odd slices = M_s^2 (64x64 tiles)
//   ysum : Yh[kq][r][o] = quarter-K partial of MallC . Z^T     (1024 blk)
//   bn_part: per-64-row partial sum/sumsq of sum of 4 quarters (256 blk)
//   bn_out : inline stats + normalize+relu+w2+b2               (256 blk)
#define B_   32
#define N_   512
#define D_   768
#define OUT_ 64
#define R_   (B_ * N_)

typedef unsigned short u16;
typedef __bf16 bf16x8 __attribute__((ext_vector_type(8)));
typedef float  f32x4  __attribute__((ext_vector_type(4)));
typedef unsigned short u16x8 __attribute__((ext_vector_type(8)));

__device__ __forceinline__ u16 f2bf(float f) {
    __hip_bfloat16 h = __float2bfloat16(f);
    return __builtin_bit_cast(u16, h);
}

__device__ __forceinline__ f32x4 mfma16(u16x8 a, u16x8 b, f32x4 c) {
    return __builtin_amdgcn_mfma_f32_16x16x32_bf16(
        __builtin_bit_cast(bf16x8, a), __builtin_bit_cast(bf16x8, b), c, 0, 0, 0);
}

__device__ __forceinline__ void gl2lds16(const void* g, void* l) {
    __builtin_amdgcn_global_load_lds(
        (const __attribute__((address_space(1))) unsigned int*)g,
        (__attribute__((address_space(3))) unsigned int*)l, 16, 0, 0);
}

// ---------------------------------------------------------------------------
// prep2: [0,512) build M (even MallC col slices) + MT | [512,1280) build Wt
// ---------------------------------------------------------------------------
__global__ __launch_bounds__(256) void prep2(
    const float* __restrict__ support, const float* __restrict__ weight,
    const float* __restrict__ epsp,
    u16* __restrict__ MallC, u16* __restrict__ MT, u16* __restrict__ Wt)
{
    const int blk = blockIdx.x, tid = threadIdx.x;
    __shared__ float t[32][33];
    if (blk < 512) {
        int s = blk >> 8, rem = blk & 255;
        int n0 = (rem >> 4) * 32, m0 = (rem & 15) * 32;
        const float f = 1.0f + epsp[0];
        const float* S = support + (size_t)s * 262144;
#pragma unroll
        for (int p = 0; p < 4; ++p) {
            int nl = p * 8 + (tid >> 5), ml = tid & 31;
            float v = S[(size_t)(n0 + nl) * 512 + m0 + ml];
            if (n0 + nl == m0 + ml) v += f;
            MallC[(size_t)(n0 + nl) * 2048 + s * 1024 + m0 + ml] = f2bf(v);
            t[nl][ml] = v;
        }
        __syncthreads();
#pragma unroll
        for (int p = 0; p < 4; ++p) {
            int ml = p * 8 + (tid >> 5), nl = tid & 31;
            MT[(size_t)s * 262144 + (size_t)(m0 + ml) * 512 + n0 + nl] = f2bf(t[nl][ml]);
        }
    } else {
        int idx = (blk - 512) * 256 + tid;          // 4*64*768 = 196608
        int k = idx / 49152, rem = idx % 49152;
        int o = rem / 768, d = rem % 768;
        int l = d >> 6, hh = d & 63;
        Wt[idx] = f2bf(weight[((size_t)l * 256 + hh * 4 + k) * 64 + o]);
    }
}

// ---------------------------------------------------------------------------
// zmsq: 64x64 tiles, 4 blocks/CU.
//  blocks 0-1023: zgemm. Swizzle: k=(bid>>3)&3, r2=(bid>>5)*8+(bid&7) so the
//    4 k-duplicates of an x-tile are co-XCD and temporally adjacent.
//    A = Wt rows k*64..+63 (gl2lds, sector-aligned). B = x rows (fp32, 4
//    lanes/row x 16 floats contiguous -> 100% sector utilization), cvt->LDS.
//    K=768, BK=64, 12 iters. Waves 2x2 of 32x32.
//  blocks 1024-1151: msq (64x64 tiles of M_s^2).
// ---------------------------------------------------------------------------
__global__ __launch_bounds__(256, 4) void zmsq(
    const u16* __restrict__ Wt, const float* __restrict__ x,
    const u16* __restrict__ MallC_in, const u16* __restrict__ MT,
    u16* __restrict__ Z, u16* __restrict__ MallC_out)
{
    __shared__ __align__(16) u16 SM[8192];           // 16 KB
    const int tid = threadIdx.x, lane = tid & 63, wid = tid >> 6;
    const int wr = wid >> 1, wc = wid & 1;
    const int lrow = lane & 15, lk8 = (lane >> 4) * 8;
    const int q = lane >> 4;
    const int bid = blockIdx.x;

    f32x4 acc[2][2] = {};

    if (bid < 1024) {
        const int k = (bid >> 3) & 3;
        const int r2 = (bid >> 5) * 8 + (bid & 7);
        const int b = r2 >> 3, m0 = (r2 & 7) * 64;

        // A staging: 8 gl2lds insts, 2 per wave (sector-aligned)
        const u16* gsrcA[2]; u16* ldstA[2];
#pragma unroll
        for (int t = 0; t < 2; ++t) {
            int idx = wid * 2 + t;                   // [0,8)
            int p = idx >> 2, sub = idx & 3;
            gsrcA[t] = Wt + (size_t)(k * 64 + sub * 16 + lrow) * 768 + p * 32 + lk8;
            ldstA[t] = SM + p * 2048 + sub * 512;
        }
        // B: thread t -> row r = t>>2 (64 rows), c4 = t&3 (16 consecutive floats)
        // 4 lanes cover 256 B contiguous per row -> full 64 B sectors.
        const int r = tid >> 2, c4 = tid & 3;
        const float* gx = x + (size_t)(b * 512 + m0 + r) * 768 + c4 * 16;
        // frag layout: subtile sub=r>>4 (512 u16): elem(rl=r&15, kg*8+j) at rl*8+kg*128
        // kg_global = c4*2, pan = c4>>1, in-pan offset = (c4&1)*256
        u16* bdst = SM + 4096 + (c4 >> 1) * 2048 + (r >> 4) * 512
                  + (c4 & 1) * 256 + (r & 15) * 8;

        for (int kk = 0; kk < 12; ++kk) {
#pragma unroll
            for (int t = 0; t < 2; ++t) gl2lds16(gsrcA[t], ldstA[t]);
#pragma unroll
            for (int t = 0; t < 2; ++t) gsrcA[t] += 64;
            f32x4 a0 = *(const f32x4*)(gx);
            f32x4 a1 = *(const f32x4*)(gx + 4);
            f32x4 a2 = *(const f32x4*)(gx + 8);
            f32x4 a3 = *(const f32x4*)(gx + 12);
            gx += 64;
            u16x8 w0, w1;
#pragma unroll
            for (int j = 0; j < 4; ++j) {
                w0[j] = f2bf(a0[j]); w0[4 + j] = f2bf(a1[j]);
                w1[j] = f2bf(a2[j]); w1[4 + j] = f2bf(a3[j]);
            }
            *(u16x8*)(bdst)       = w0;              // kg_global
            *(u16x8*)(bdst + 128) = w1;              // kg_global + 1
            __syncthreads();
#pragma unroll
            for (int p = 0; p < 2; ++p) {
                u16x8 af[2], bq[2];
#pragma unroll
                for (int f = 0; f < 2; ++f)
                    af[f] = *(const u16x8*)(SM + p * 2048 + (wr * 2 + f) * 512 + lane * 8);
#pragma unroll
                for (int f = 0; f < 2; ++f)
                    bq[f] = *(const u16x8*)(SM + 4096 + p * 2048 + (wc * 2 + f) * 512 + lane * 8);
#pragma unroll
                for (int fi = 0; fi < 2; ++fi)
#pragma unroll
                    for (int fj = 0; fj < 2; ++fj)
                        acc[fi][fj] = mfma16(af[fi], bq[fj], acc[fi][fj]);
            }
            __syncthreads();
        }
        // epilogue: per-wave repack 32x32 (stride 40 u16), vector stores
        u16* Rw = SM + wid * 1280;
#pragma unroll
        for (int fi = 0; fi < 2; ++fi)
#pragma unroll
            for (int fj = 0; fj < 2; ++fj)
#pragma unroll
                for (int rr = 0; rr < 4; ++rr)
                    Rw[(fi * 16 + q * 4 + rr) * 40 + fj * 16 + lrow] = f2bf(acc[fi][fj][rr]);
        __syncthreads();
        const int r3 = lane >> 1, cc = (lane & 1) * 16;
        u16x8 v0 = *(const u16x8*)(Rw + r3 * 40 + cc);
        u16x8 v1 = *(const u16x8*)(Rw + r3 * 40 + cc + 8);
        u16* zp = Z + (size_t)(b * 64 + wr * 32 + r3) * 2048 + k * 512 + m0 + wc * 32 + cc;
        *(u16x8*)(zp)     = v0;
        *(u16x8*)(zp + 8) = v1;
    } else {
        const int lb = bid - 1024;
        const int s = lb >> 6, i0 = ((lb >> 3) & 7) * 64, j0 = (lb & 7) * 64;

        const u16* gsrc[4]; u16* ldst[4];
#pragma unroll
        for (int t = 0; t < 4; ++t) {
            int idx = wid * 4 + t;                   // [0,16)
            if (idx < 8) {
                int p = idx >> 2, sub = idx & 3;
                gsrc[t] = MallC_in + (size_t)(i0 + sub * 16 + lrow) * 2048 + s * 1024 + p * 32 + lk8;
                ldst[t] = SM + p * 2048 + sub * 512;
            } else {
                int i2 = idx - 8;
                int p = i2 >> 2, sub = i2 & 3;
                gsrc[t] = MT + (size_t)s * 262144 + (size_t)(j0 + sub * 16 + lrow) * 512 + p * 32 + lk8;
                ldst[t] = SM + 4096 + p * 2048 + sub * 512;
            }
        }
        for (int kk = 0; kk < 8; ++kk) {
#pragma unroll
            for (int t = 0; t < 4; ++t) gl2lds16(gsrc[t], ldst[t]);
#pragma unroll
            for (int t = 0; t < 4; ++t) gsrc[t] += 64;
            __syncthreads();
#pragma unroll
            for (int p = 0; p < 2; ++p) {
                u16x8 af[2], bq[2];
#pragma unroll
                for (int f = 0; f < 2; ++f)
                    af[f] = *(const u16x8*)(SM + p * 2048 + (wr * 2 + f) * 512 + lane * 8);
#pragma unroll
                for (int f = 0; f < 2; ++f)
                    bq[f] = *(const u16x8*)(SM + 4096 + p * 2048 + (wc * 2 + f) * 512 + lane * 8);
#pragma unroll
                for (int fi = 0; fi < 2; ++fi)
#pragma unroll
                    for (int fj = 0; fj < 2; ++fj)
                        acc[fi][fj] = mfma16(af[fi], bq[fj], acc[fi][fj]);
            }
            __syncthreads();
        }
#pragma unroll
        for (int fi = 0; fi < 2; ++fi)
#pragma unroll
            for (int fj = 0; fj < 2; ++fj)
#pragma unroll
                for (int rr = 0; rr < 4; ++rr) {
                    int n = i0 + wr * 32 + fi * 16 + q * 4 + rr;
                    int c = j0 + wc * 32 + fj * 16 + lrow;
                    MallC_out[(size_t)n * 2048 + (2 * s + 1) * 512 + c] = f2bf(acc[fi][fj][rr]);
                }
    }
}

// ---------------------------------------------------------------------------
// ysum: 1024 blocks (4/CU). kq = bid>>8, rt = bid&255: r0 = rt*64, b = rt>>3,
// n0 = r0&511. Tile 64r x 64o, K=512 (quarter), BK=64, 8 iters.
// ---------------------------------------------------------------------------
__global__ __launch_bounds__(256, 4) void ysum(
    const u16* __restrict__ G, const u16* __restrict__ Z, float* __restrict__ Yh)
{
    __shared__ __align__(16) u16 SM[8192];
    const int tid = threadIdx.x, lane = tid & 63, wid = tid >> 6;
    const int wr = wid >> 1, wc = wid & 1;
    const int lrow = lane & 15, lk8 = (lane >> 4) * 8;
    const int bid = blockIdx.x;
    const int kq = bid >> 8, rt = bid & 255;
    const int r0 = rt * 64, b = rt >> 3, n0 = r0 & 511;

    const u16* gsrc[4]; u16* ldst[4];
#pragma unroll
    for (int t = 0; t < 4; ++t) {
        int idx = wid * 4 + t;
        if (idx < 8) {
            int p = idx >> 2, sub = idx & 3;
            gsrc[t] = G + (size_t)(n0 + sub * 16 + lrow) * 2048 + kq * 512 + p * 32 + lk8;
            ldst[t] = SM + p * 2048 + sub * 512;
        } else {
            int i2 = idx - 8;
            int p = i2 >> 2, sub = i2 & 3;
            gsrc[t] = Z + (size_t)(b * 64 + sub * 16 + lrow) * 2048 + kq * 512 + p * 32 + lk8;
            ldst[t] = SM + 4096 + p * 2048 + sub * 512;
        }
    }
    f32x4 acc[2][2] = {};
    for (int kk = 0; kk < 8; ++kk) {
#pragma unroll
        for (int t = 0; t < 4; ++t) gl2lds16(gsrc[t], ldst[t]);
#pragma unroll
        for (int t = 0; t < 4; ++t) gsrc[t] += 64;
        __syncthreads();
#pragma unroll
        for (int p = 0; p < 2; ++p) {
            u16x8 af[2], bq[2];
#pragma unroll
            for (int f = 0; f < 2; ++f)
                af[f] = *(const u16x8*)(SM + p * 2048 + (wr * 2 + f) * 512 + lane * 8);
#pragma unroll
            for (int f = 0; f < 2; ++f)
                bq[f] = *(const u16x8*)(SM + 4096 + p * 2048 + (wc * 2 + f) * 512 + lane * 8);
#pragma unroll
            for (int fi = 0; fi < 2; ++fi)
#pragma unroll
                for (int fj = 0; fj < 2; ++fj)
                    acc[fi][fj] = mfma16(af[fi], bq[fj], acc[fi][fj]);
        }
        __syncthreads();
    }
    const int q = lane >> 4;
    float* Yk = Yh + (size_t)kq * R_ * 64;
#pragma unroll
    for (int fi = 0; fi < 2; ++fi)
#pragma unroll
        for (int fj = 0; fj < 2; ++fj)
#pragma unroll
            for (int rr = 0; rr < 4; ++rr) {
                int r2 = r0 + wr * 32 + fi * 16 + q * 4 + rr;
                int o  = wc * 32 + fj * 16 + lrow;
                Yk[(size_t)r2 * 64 + o] = acc[fi][fj][rr];
            }
}

// ---------------------------------------------------------------------------
// bn_part: grid 256, block j: rows j*64..+63, v = sum of 4 Yh quarters.
// ---------------------------------------------------------------------------
__global__ __launch_bounds__(256) void bn_part(
    const float* __restrict__ Yh, float* __restrict__ part)
{
    const int blk = blockIdx.x, tid = threadIdx.x;
    const int o = tid & 63, g = tid >> 6;
    float s = 0.f, s2 = 0.f;
#pragma unroll
    for (int p = 0; p < 16; ++p) {
        int r = blk * 64 + p * 4 + g;
        size_t off = (size_t)r * 64 + o;
        float v = Yh[off] + Yh[(size_t)R_ * 64 + off]
                + Yh[(size_t)2 * R_ * 64 + off] + Yh[(size_t)3 * R_ * 64 + off];
        s += v; s2 += v * v;
    }
    __shared__ float ls[4][64], ls2[4][64];
    ls[g][o] = s; ls2[g][o] = s2;
    __syncthreads();
    if (tid < 64) {
        float t = 0.f, t2 = 0.f;
#pragma unroll
        for (int g2 = 0; g2 < 4; ++g2) { t += ls[g2][tid]; t2 += ls2[g2][tid]; }
        part[blk * 128 + tid]      = t;
        part[blk * 128 + 64 + tid] = t2;
    }
}

// ---------------------------------------------------------------------------
// bn_out: inline stats from partials, then normalize+relu+w2+b2.
// ---------------------------------------------------------------------------
__global__ __launch_bounds__(256) void bn_out(
    const float* __restrict__ Yh, const float* __restrict__ part,
    const float* __restrict__ gamma, const float* __restrict__ beta,
    const float* __restrict__ w2, const float* __restrict__ b2,
    float* __restrict__ out)
{
    __shared__ float ys[64 * 68];
    __shared__ float w2s[64 * 65];
    __shared__ float red[4][64], red2[4][64];
    __shared__ float sa[64], sh[64];
    const int tid = threadIdx.x;
    const int r0 = blockIdx.x * 64;
    const int o = tid & 63, g = tid >> 6;
    {
        float s = 0.f, s2 = 0.f;
        for (int p = g; p < 256; p += 4) {
            s  += part[p * 128 + o];
            s2 += part[p * 128 + 64 + o];
        }
        red[g][o] = s; red2[g][o] = s2;
    }
#pragma unroll
    for (int i = 0; i < 16; ++i) {
        int idx = tid + i * 256;
        w2s[(idx >> 6) * 65 + (idx & 63)] = w2[idx];
    }
    __syncthreads();
    if (tid < 64) {
        float t0 = red[0][tid] + red[1][tid] + red[2][tid] + red[3][tid];
        float t2 = red2[0][tid] + red2[1][tid] + red2[2][tid] + red2[3][tid];
        float mean = t0 * (1.0f / R_);
        float var  = t2 * (1.0f / R_) - mean * mean;
        float a = rsqrtf(var + 1e-5f) * gamma[tid];
        sa[tid] = a;
        sh[tid] = beta[tid] - mean * a;
    }
    __syncthreads();
    {
        float a = sa[o], bsh = sh[o];
#pragma unroll
        for (int p = 0; p < 16; ++p) {
            int rl = p * 4 + g;
            size_t off = (size_t)(r0 + rl) * 64 + o;
            float v = Yh[off] + Yh[(size_t)R_ * 64 + off]
                    + Yh[(size_t)2 * R_ * 64 + off] + Yh[(size_t)3 * R_ * 64 + off];
            ys[o * 68 + rl] = fmaxf(fmaf(v, a, bsh), 0.f);
        }
    }
    __syncthreads();
    float acc[16];
    float bb = b2[o];
#pragma unroll
    for (int j = 0; j < 16; ++j) acc[j] = bb;
    for (int c = 0; c < 64; ++c) {
        float wv = w2s[o * 65 + c];
        const float* yr = ys + c * 68 + g * 16;
        f32x4 y0 = *(const f32x4*)(yr);
        f32x4 y1 = *(const f32x4*)(yr + 4);
        f32x4 y2 = *(const f32x4*)(yr + 8);
        f32x4 y3 = *(const f32x4*)(yr + 12);
#pragma unroll
        for (int j = 0; j < 4; ++j) {
            acc[j]      = fmaf(wv, y0[j], acc[j]);
            acc[4 + j]  = fmaf(wv, y1[j], acc[4 + j]);
            acc[8 + j]  = fmaf(wv, y2[j], acc[8 + j]);
            acc[12 + j] = fmaf(wv, y3[j], acc[12 + j]);
        }
    }
#pragma unroll
    for (int j = 0; j < 16; ++j)
        out[(size_t)(r0 + g * 16 + j) * OUT_ + o] = acc[j];
}

// ---------------------------------------------------------------------------
extern "C" void kernel_launch(void* const* d_in, const int* in_sizes, int n_in,
                              void* d_out, int out_size, void* d_ws, size_t ws_size,
                              hipStream_t stream)
{
    const float* x       = (const float*)d_in[0];
    const float* support = (const float*)d_in[1];
    const float* weight  = (const float*)d_in[2];
    const float* eps     = (const float*)d_in[3];
    const float* gamma   = (const float*)d_in[4];
    const float* beta    = (const float*)d_in[5];
    const float* w2      = (const float*)d_in[6];
    const float* b2      = (const float*)d_in[7];
    float* out = (float*)d_out;

    char* ws = (char*)d_ws;
    u16*   MallC = (u16*)(ws);                      //  2,097,152  [512][2048]
    u16*   MT    = (u16*)(ws + 2097152);            //  1,048,576
    u16*   Wt    = (u16*)(ws + 3145728);            //    393,216  [256][768]
    u16*   Z     = (u16*)(ws + 3538944);            //  8,388,608  [2048][2048]
    float* Yh    = (float*)(ws + 11927552);         // 16,777,216  (4 quarters)
    float* part  = (float*)(ws + 28704768);         //    131,072

    prep2  <<<1280, 256, 0, stream>>>(support, weight, eps, MallC, MT, Wt);
    zmsq   <<<1152, 256, 0, stream>>>(Wt, x, MallC, MT, Z, MallC);
    ysum   <<<1024, 256, 0, stream>>>(MallC, Z, Yh);
    bn_part<<<256,  256, 0, stream>>>(Yh, part);
    bn_out <<<256,  256, 0, stream>>>(Yh, part, gamma, beta, w2, b2, out);
}